// Round 1
// baseline (222.105 us; speedup 1.0000x reference)
//
#include <hip/hip_runtime.h>

#define S_LEN 2048
#define D_MODEL 512

typedef __attribute__((ext_vector_type(8))) short s8v;   // 8 x bf16 (4 VGPRs) MFMA A/B frag
typedef __attribute__((ext_vector_type(4))) float f4v;   // MFMA C/D frag
typedef __attribute__((ext_vector_type(4))) short s4v;
typedef __attribute__((ext_vector_type(4))) int   i4v;

#define MFMA __builtin_amdgcn_mfma_f32_16x16x32_bf16

__device__ inline short f2bf(float x) {            // fp32 -> bf16 RNE
    union { float f; unsigned u; } v; v.f = x;
    unsigned r = v.u + 0x7fffu + ((v.u >> 16) & 1u);
    return (short)(r >> 16);
}

template <int C>
__device__ inline float dppf(float x) {            // DPP permute within 16-lane row
    int i = __builtin_bit_cast(int, x);
    i = __builtin_amdgcn_update_dpp(0, i, C, 0xF, 0xF, true);
    return __builtin_bit_cast(float, i);
}
// reduce across the 16 lanes of a DPP row (MFMA C-layout: one row = one quad's 16 lanes)
__device__ inline float rowmax16(float x) {
    x = fmaxf(x, dppf<0xB1>(x));    // quad_perm xor1
    x = fmaxf(x, dppf<0x4E>(x));    // quad_perm xor2
    x = fmaxf(x, dppf<0x141>(x));   // row_half_mirror
    x = fmaxf(x, dppf<0x140>(x));   // row_mirror
    return x;
}
__device__ inline float rowsum16(float x) {
    x += dppf<0xB1>(x);
    x += dppf<0x4E>(x);
    x += dppf<0x141>(x);
    x += dppf<0x140>(x);
    return x;
}

// ---------------- prep: transpose weights to bf16 ----------------
__global__ __launch_bounds__(256) void prep_kernel(
    const float* __restrict__ Wo, const float* __restrict__ Wq,
    const float* __restrict__ Wk, const float* __restrict__ Wv,
    short* __restrict__ WoT, short* __restrict__ WqT,
    short* __restrict__ WkT, short* __restrict__ WvT)
{
    int idx = blockIdx.x * 256 + threadIdx.x;
    if (idx < 512 * 512) {
        int o = idx >> 9, i = idx & 511;
        WoT[idx] = f2bf(Wo[i * 512 + o]);          // WoT[out][in]
    } else {
        int j = idx - 512 * 512;                   // 0..12287
        int w = j >> 12, r = j & 4095;
        int e = r >> 6, d = r & 63;
        const float* W = (w == 0) ? Wq : (w == 1) ? Wk : Wv;
        short* WT = (w == 0) ? WqT : (w == 1) ? WkT : WvT;
        WT[r] = f2bf(W[d * 64 + e]);               // WT[e][d]
    }
}

// ---------------- projections: qp/kp [b][h][s][64], vpT [b][h][e][s] ----------------
__global__ __launch_bounds__(256) void proj_kernel(
    const float* __restrict__ q, const float* __restrict__ k, const float* __restrict__ v,
    const float* __restrict__ bq, const float* __restrict__ bk, const float* __restrict__ bv,
    const short* __restrict__ WqT, const short* __restrict__ WkT, const short* __restrict__ WvT,
    short* __restrict__ qp, short* __restrict__ kp, short* __restrict__ vpT)
{
    const int t = blockIdx.z >> 2;     // 0:q 1:k 2:v
    const int b = blockIdx.z & 3;
    const int h = blockIdx.y;
    const int qt = blockIdx.x;         // 16 row-tiles of 128
    const int w = threadIdx.x >> 6, lane = threadIdx.x & 63;
    const int l = lane & 15, qd = lane >> 4;

    const float* X    = (t == 0) ? q   : (t == 1) ? k   : v;
    const float* bias = (t == 0) ? bq  : (t == 1) ? bk  : bv;
    const short* WT   = (t == 0) ? WqT : (t == 1) ? WkT : WvT;

    const int s0 = qt * 128 + w * 32;

    // A frags direct from global fp32, converted
    s8v a[2][2];
#pragma unroll
    for (int mt = 0; mt < 2; mt++)
#pragma unroll
        for (int kk = 0; kk < 2; kk++) {
            const float* p = X + (size_t)(b * S_LEN + s0 + mt * 16 + l) * 512 + h * 64 + kk * 32 + qd * 8;
            f4v x0 = *(const f4v*)p;
            f4v x1 = *(const f4v*)(p + 4);
            s8v fr;
            fr[0] = f2bf(x0[0]); fr[1] = f2bf(x0[1]); fr[2] = f2bf(x0[2]); fr[3] = f2bf(x0[3]);
            fr[4] = f2bf(x1[0]); fr[5] = f2bf(x1[1]); fr[6] = f2bf(x1[2]); fr[7] = f2bf(x1[3]);
            a[mt][kk] = fr;
        }
    // B frags (whole 64x64 W) held in registers
    s8v wf[4][2];
#pragma unroll
    for (int nt = 0; nt < 4; nt++)
#pragma unroll
        for (int kk = 0; kk < 2; kk++)
            wf[nt][kk] = *(const s8v*)(WT + (nt * 16 + l) * 64 + kk * 32 + qd * 8);

    const f4v fz = {0.f, 0.f, 0.f, 0.f};
    f4v acc[2][4];
#pragma unroll
    for (int mt = 0; mt < 2; mt++)
#pragma unroll
        for (int nt = 0; nt < 4; nt++) acc[mt][nt] = fz;

#pragma unroll
    for (int kk = 0; kk < 2; kk++)
#pragma unroll
        for (int nt = 0; nt < 4; nt++)
#pragma unroll
            for (int mt = 0; mt < 2; mt++)
                acc[mt][nt] = MFMA(a[mt][kk], wf[nt][kk], acc[mt][nt], 0, 0, 0);

    // fold softmax scale * log2(e) into Q so attention uses exp2 directly
    const float SC = 0.125f * 1.442695041f;

    if (t < 2) {
        short* out = (t == 0) ? qp : kp;
#pragma unroll
        for (int nt = 0; nt < 4; nt++) {
            float bb = bias[nt * 16 + l];
#pragma unroll
            for (int mt = 0; mt < 2; mt++)
#pragma unroll
                for (int r = 0; r < 4; r++) {
                    float val = acc[mt][nt][r] + bb;
                    if (t == 0) val *= SC;
                    int s = s0 + mt * 16 + qd * 4 + r;
                    out[((size_t)(b * 8 + h) * S_LEN + s) * 64 + nt * 16 + l] = f2bf(val);
                }
        }
    } else {
        // vpT[b][h][e][s]: 4 consecutive s per lane -> 8B packed stores
#pragma unroll
        for (int nt = 0; nt < 4; nt++) {
            float bb = bias[nt * 16 + l];
            int e = nt * 16 + l;
#pragma unroll
            for (int mt = 0; mt < 2; mt++) {
                s4v pk;
#pragma unroll
                for (int r = 0; r < 4; r++) pk[r] = f2bf(acc[mt][nt][r] + bb);
                *(s4v*)(vpT + ((size_t)(b * 8 + h) * 64 + e) * S_LEN + s0 + mt * 16 + qd * 4) = pk;
            }
        }
    }
}

// ---------------- flash attention: BM=128 (4 waves x 32 rows), BN=64 ----------------
__global__ __launch_bounds__(256) void attn_kernel(
    const short* __restrict__ qp, const short* __restrict__ kp, const short* __restrict__ vpT,
    const int* __restrict__ valid_lens, short* __restrict__ ctx)
{
    __shared__ short lK[64 * 64];        // XOR-swizzled: addr(r,g) = r*64 + ((g^(r&7))*8)
    __shared__ short lV[64 * 64];        // same swizzle, rows = e, cols = keys
    __shared__ short lP[4 * 32 * 72];    // per-wave P scratch, stride 72 (16B-aligned rows)

    const int b = blockIdx.z, h = blockIdx.y, qt = blockIdx.x;
    const int w = threadIdx.x >> 6, lane = threadIdx.x & 63;
    const int l = lane & 15, qd = lane >> 4;
    const int vlen = valid_lens[b];
    const int ntiles = (vlen + 63) >> 6;   // skip fully-masked tiles: exp(-1000-m)==0 exactly

    const size_t slab = (size_t)(b * 8 + h) * S_LEN * 64;
    const short* Qs = qp + slab;
    const short* Ks = kp + slab;
    const short* Vs = vpT + slab;

    const int s0 = qt * 128 + w * 32;
    s8v qf[2][2];
#pragma unroll
    for (int mt = 0; mt < 2; mt++)
#pragma unroll
        for (int kk = 0; kk < 2; kk++)
            qf[mt][kk] = *(const s8v*)(Qs + (size_t)(s0 + mt * 16 + l) * 64 + kk * 32 + qd * 8);

    const f4v fz = {0.f, 0.f, 0.f, 0.f};
    f4v O[2][4];
    float m_i[2][4], l_i[2][4];
#pragma unroll
    for (int mt = 0; mt < 2; mt++)
#pragma unroll
        for (int r = 0; r < 4; r++) { m_i[mt][r] = -1e30f; l_i[mt][r] = 0.f; }
#pragma unroll
    for (int mt = 0; mt < 2; mt++)
#pragma unroll
        for (int ne = 0; ne < 4; ne++) O[mt][ne] = fz;

    short* lPw = lP + w * 32 * 72;

    for (int kb = 0; kb < ntiles; kb++) {
        // stage K,V tiles (swizzled so B-frag reads are conflict-free)
#pragma unroll
        for (int i = 0; i < 2; i++) {
            int c = i * 256 + threadIdx.x;     // 0..511 16B-chunks
            int r = c >> 3, g = c & 7;
            i4v kv = *(const i4v*)(Ks + (size_t)kb * 64 * 64 + c * 8);
            *(i4v*)(lK + r * 64 + ((g ^ (r & 7)) * 8)) = kv;
            i4v vv = *(const i4v*)(Vs + (size_t)r * S_LEN + kb * 64 + g * 8);
            *(i4v*)(lV + r * 64 + ((g ^ (r & 7)) * 8)) = vv;
        }
        __syncthreads();

        // S = Q K^T (Q pre-scaled); D[row=query][col=key]
        f4v sf[2][4];
#pragma unroll
        for (int mt = 0; mt < 2; mt++)
#pragma unroll
            for (int nt = 0; nt < 4; nt++) sf[mt][nt] = fz;
#pragma unroll
        for (int nt = 0; nt < 4; nt++) {
            s8v k0 = *(const s8v*)(lK + (nt * 16 + l) * 64 + ((qd ^ (l & 7)) * 8));
            s8v k1 = *(const s8v*)(lK + (nt * 16 + l) * 64 + (((4 + qd) ^ (l & 7)) * 8));
#pragma unroll
            for (int mt = 0; mt < 2; mt++) {
                sf[mt][nt] = MFMA(qf[mt][0], k0, sf[mt][nt], 0, 0, 0);
                sf[mt][nt] = MFMA(qf[mt][1], k1, sf[mt][nt], 0, 0, 0);
            }
        }

        // boundary-tile key mask
        if (kb == ntiles - 1 && (vlen & 63)) {
#pragma unroll
            for (int nt = 0; nt < 4; nt++) {
                int key = kb * 64 + nt * 16 + l;
                if (key >= vlen) {
#pragma unroll
                    for (int mt = 0; mt < 2; mt++)
#pragma unroll
                        for (int r = 0; r < 4; r++) sf[mt][nt][r] = -1e30f;
                }
            }
        }

        // online softmax (exp2 domain) + P -> LDS (bf16)
#pragma unroll
        for (int mt = 0; mt < 2; mt++)
#pragma unroll
            for (int r = 0; r < 4; r++) {
                float mx = fmaxf(fmaxf(sf[mt][0][r], sf[mt][1][r]),
                                 fmaxf(sf[mt][2][r], sf[mt][3][r]));
                mx = rowmax16(mx);
                float mnew = fmaxf(m_i[mt][r], mx);
                float alpha = __builtin_amdgcn_exp2f(m_i[mt][r] - mnew);
                m_i[mt][r] = mnew;
                float p0 = __builtin_amdgcn_exp2f(sf[mt][0][r] - mnew);
                float p1 = __builtin_amdgcn_exp2f(sf[mt][1][r] - mnew);
                float p2 = __builtin_amdgcn_exp2f(sf[mt][2][r] - mnew);
                float p3 = __builtin_amdgcn_exp2f(sf[mt][3][r] - mnew);
                float ps = rowsum16((p0 + p1) + (p2 + p3));
                l_i[mt][r] = l_i[mt][r] * alpha + ps;
#pragma unroll
                for (int ne = 0; ne < 4; ne++) O[mt][ne][r] *= alpha;
                int row = mt * 16 + qd * 4 + r;
                lPw[row * 72 +  0 + l] = f2bf(p0);
                lPw[row * 72 + 16 + l] = f2bf(p1);
                lPw[row * 72 + 32 + l] = f2bf(p2);
                lPw[row * 72 + 48 + l] = f2bf(p3);
            }

        // O += P V   (A-frags from wave-private LDS; compiler inserts lgkmcnt)
        s8v pa[2][2];
#pragma unroll
        for (int mt = 0; mt < 2; mt++)
#pragma unroll
            for (int kk = 0; kk < 2; kk++)
                pa[mt][kk] = *(const s8v*)(lPw + (mt * 16 + l) * 72 + kk * 32 + qd * 8);
#pragma unroll
        for (int ne = 0; ne < 4; ne++) {
            s8v v0 = *(const s8v*)(lV + (ne * 16 + l) * 64 + ((qd ^ (l & 7)) * 8));
            s8v v1 = *(const s8v*)(lV + (ne * 16 + l) * 64 + (((4 + qd) ^ (l & 7)) * 8));
#pragma unroll
            for (int mt = 0; mt < 2; mt++) {
                O[mt][ne] = MFMA(pa[mt][0], v0, O[mt][ne], 0, 0, 0);
                O[mt][ne] = MFMA(pa[mt][1], v1, O[mt][ne], 0, 0, 0);
            }
        }
        __syncthreads();
    }

    // normalize + write ctx[b][s][h*64+e] (bf16, head-major concat)
#pragma unroll
    for (int mt = 0; mt < 2; mt++)
#pragma unroll
        for (int r = 0; r < 4; r++) {
            float inv = 1.0f / l_i[mt][r];
            int s = s0 + mt * 16 + qd * 4 + r;
            size_t base = ((size_t)(b * S_LEN + s)) * 512 + h * 64;
#pragma unroll
            for (int ne = 0; ne < 4; ne++)
                ctx[base + ne * 16 + l] = f2bf(O[mt][ne][r] * inv);
        }
}

// ---------------- output projection: [8192,512] = ctx @ Wo + bo ----------------
__global__ __launch_bounds__(256) void outproj_kernel(
    const short* __restrict__ ctx, const short* __restrict__ WoT,
    const float* __restrict__ bo, float* __restrict__ out)
{
    __shared__ short lB[64 * 520];   // Wo^T tile, padded stride (kills 1024B-stride alias)
    __shared__ short lA[128 * 40];   // A k-slab, padded stride 40 shorts (80B)

    const int rb = blockIdx.x * 128;
    const int nb = blockIdx.y * 64;
    const int w = threadIdx.x >> 6, lane = threadIdx.x & 63;
    const int l = lane & 15, qd = lane >> 4;

    {   // stage B tile once: 64 rows x 512
        int n = threadIdx.x >> 2, c0 = threadIdx.x & 3;
#pragma unroll
        for (int i = 0; i < 16; i++) {
            int g = i * 4 + c0;  // 64 granules of 8 shorts
            i4v x = *(const i4v*)(WoT + (size_t)(nb + n) * 512 + g * 8);
            *(i4v*)(lB + n * 520 + g * 8) = x;
        }
    }
    __syncthreads();

    const f4v fz = {0.f, 0.f, 0.f, 0.f};
    f4v acc[2][4];
#pragma unroll
    for (int mt = 0; mt < 2; mt++)
#pragma unroll
        for (int nt = 0; nt < 4; nt++) acc[mt][nt] = fz;

    for (int ko = 0; ko < 16; ko++) {
        {   // stage A slab 128x32
            int r = threadIdx.x >> 1, hp = threadIdx.x & 1;
            const short* src = ctx + (size_t)(rb + r) * 512 + ko * 32 + hp * 16;
            i4v x0 = *(const i4v*)src;
            i4v x1 = *(const i4v*)(src + 8);
            *(i4v*)(lA + r * 40 + hp * 16) = x0;
            *(i4v*)(lA + r * 40 + hp * 16 + 8) = x1;
        }
        __syncthreads();
        s8v af[2];
#pragma unroll
        for (int mt = 0; mt < 2; mt++)
            af[mt] = *(const s8v*)(lA + (w * 32 + mt * 16 + l) * 40 + qd * 8);
#pragma unroll
        for (int nt = 0; nt < 4; nt++) {
            s8v bfr = *(const s8v*)(lB + (nt * 16 + l) * 520 + ko * 32 + qd * 8);
#pragma unroll
            for (int mt = 0; mt < 2; mt++)
                acc[mt][nt] = MFMA(af[mt], bfr, acc[mt][nt], 0, 0, 0);
        }
        __syncthreads();
    }

#pragma unroll
    for (int nt = 0; nt < 4; nt++) {
        float bias = bo[nb + nt * 16 + l];
#pragma unroll
        for (int mt = 0; mt < 2; mt++)
#pragma unroll
            for (int r = 0; r < 4; r++) {
                int row = rb + w * 32 + mt * 16 + qd * 4 + r;
                out[(size_t)row * 512 + nb + nt * 16 + l] = acc[mt][nt][r] + bias;
            }
    }
}

extern "C" void kernel_launch(void* const* d_in, const int* in_sizes, int n_in,
                              void* d_out, int out_size, void* d_ws, size_t ws_size,
                              hipStream_t stream)
{
    const float* q  = (const float*)d_in[0];
    const float* k  = (const float*)d_in[1];
    const float* v  = (const float*)d_in[2];
    const float* Wq = (const float*)d_in[3];
    const float* bq = (const float*)d_in[4];
    const float* Wk = (const float*)d_in[5];
    const float* bk = (const float*)d_in[6];
    const float* Wv = (const float*)d_in[7];
    const float* bv = (const float*)d_in[8];
    const float* Wo = (const float*)d_in[9];
    const float* bo = (const float*)d_in[10];
    const int*   vl = (const int*)d_in[11];
    float* out = (float*)d_out;

    char* ws = (char*)d_ws;
    const size_t SL = (size_t)4 * 8 * S_LEN * 64 * sizeof(short);  // 8 MiB per tensor
    short* qp  = (short*)(ws);
    short* kp  = (short*)(ws + SL);
    short* vpT = (short*)(ws + 2 * SL);
    short* ctx = (short*)(ws + 3 * SL);
    short* WoT = (short*)(ws + 4 * SL);
    short* WqT = (short*)(ws + 4 * SL + 512 * 512 * sizeof(short));
    short* WkT = WqT + 4096;
    short* WvT = WkT + 4096;

    prep_kernel<<<1072, 256, 0, stream>>>(Wo, Wq, Wk, Wv, WoT, WqT, WkT, WvT);
    proj_kernel<<<dim3(16, 8, 12), 256, 0, stream>>>(q, k, v, bq, bk, bv,
                                                     WqT, WkT, WvT, qp, kp, vpT);
    attn_kernel<<<dim3(16, 8, 4), 256, 0, stream>>>(qp, kp, vpT, vl, ctx);
    outproj_kernel<<<dim3(64, 8), 256, 0, stream>>>(ctx, WoT, bo, out);
}